// Round 2
// baseline (260.937 us; speedup 1.0000x reference)
//
#include <hip/hip_runtime.h>
#include <stdint.h>

typedef unsigned short u16;
typedef __attribute__((ext_vector_type(8))) short bf16x8;   // 8 bf16 = 4 VGPRs
typedef __attribute__((ext_vector_type(4))) float f32x4;

#define NUM_B 2
#define SEQ   2048
#define SEQP  2080      // padded V row stride
#define NH    16
#define HD    128
#define EMB   2048      // NH*HD
#define N3    6144      // 3*EMB
#define MM    4096      // NUM_B*SEQ
#define QT    64        // flash q-rows per block (2 waves)
#define WQ    32        // flash q-rows per wave
#define KT    32        // flash keys per k-tile
#define NTILE (SEQ / KT)

// ---- GEMM tile params ----
#define BM 128
#define BN 256
#define BK 64
#define NT_K (EMB / BK)   // 32 K-tiles

__device__ __forceinline__ u16 f2bf(float f) {
  union { float f; unsigned u; } c; c.f = f;
  return (u16)((c.u + 0x7FFFu + ((c.u >> 16) & 1u)) >> 16);   // RNE
}
__device__ __forceinline__ void async16(const void* g, void* l) {
  __builtin_amdgcn_global_load_lds(
      (const __attribute__((address_space(1))) void*)g,
      (__attribute__((address_space(3))) void*)l, 16, 0, 0);
}

#define GBAR()   asm volatile("s_barrier" ::: "memory")
#define WLGKM0() asm volatile("s_waitcnt lgkmcnt(0)" ::: "memory")

// ---------------- prep kernels ----------------

__global__ void k_cvt_bf16(const float* __restrict__ in, u16* __restrict__ out, int n4) {
  int i = blockIdx.x * blockDim.x + threadIdx.x;
  if (i >= n4) return;
  const float4 v = ((const float4*)in)[i];
  ushort4 o;
  o.x = f2bf(v.x); o.y = f2bf(v.y); o.z = f2bf(v.z); o.w = f2bf(v.w);
  ((ushort4*)out)[i] = o;
}

// W [EMB][N3] fp32 -> Wt [N3][EMB] bf16
__global__ void k_transpose_w(const float* __restrict__ W, u16* __restrict__ Wt) {
  __shared__ float t[32][33];
  int n0 = blockIdx.x * 32, k0 = blockIdx.y * 32;
  int tx = threadIdx.x, ty = threadIdx.y;
  #pragma unroll
  for (int i = ty; i < 32; i += 8)
    t[i][tx] = W[(size_t)(k0 + i) * N3 + n0 + tx];
  __syncthreads();
  #pragma unroll
  for (int i = ty; i < 32; i += 8)
    Wt[(size_t)(n0 + i) * EMB + k0 + tx] = f2bf(t[tx][i]);
}

// sincos table for t = s*HD + d; double-precision sincos matches numpy fp32 tables
__global__ void k_sincos(float2* __restrict__ tab) {
  int i = blockIdx.x * blockDim.x + threadIdx.x;   // 0 .. SEQ*HD-1
  double t = (double)i;
  tab[i] = make_float2((float)cos(t), (float)sin(t));
}

// ---------------- QKV GEMM: 128x256, BK=64, 8 waves, 2-phase, DEEP pipeline ----------------
// Buffers: A triple-buffered (consumed across ph0+ph1), B double-buffered
// (fully reg-cached during ph0). LDS = 3*16 + 2*32 = 112 KB, 1 block/CU.
// Per tile t (Ap = lsA[t%3], Bp = lsB[t&1]):
//  ph0: ds_read bfr all [4nf][2kk] (8 b128) + afr rows 0-31 (4 b128)
//       issue stageA(t+2) -> lsA[(t+2)%3]   (drained at t-1.ph1 end-barrier)
//       barrier; lgkmcnt(0); setprio(1); 16 MFMA (acc[0..1][*]); setprio(0); barrier
//  ph1: ds_read afr rows 32-63 (4 b128)
//       issue stageB(t+2) -> lsB[t&1]       (drained at t.ph0 end-barrier)
//       s_waitcnt vmcnt(6)  -> lands A(t+1) (issued t-1.ph0, 3 phases ago) and
//                              B(t+1) (issued t-1.ph1, 2 phases ago); keeps
//                              A(t+2)+B(t+2) (6 loads) in flight. Never 0 in loop.
//       barrier; lgkmcnt(0); setprio(1); 16 MFMA (acc[2..3][*]); setprio(0); barrier
// LDS swizzle (T2, verified conflict-free in R1): slot quad = quad ^ (row&7),
// applied to the per-lane GLOBAL source (dest linear) and to the ds_read quad.
// Wave layout: 8 waves = 2(M) x 4(N), per-wave 64x64; N-strips keep both halves
// of each RoPE pair (d, d+64) in-wave.
__global__ __launch_bounds__(512, 2) void k_gemm_qkv(
    const u16* __restrict__ xb, const u16* __restrict__ wt,
    const float* __restrict__ bias, const float2* __restrict__ tab,
    u16* __restrict__ qb, u16* __restrict__ kb, u16* __restrict__ vbt)
{
  __shared__ __align__(16) u16 lsA[3][BM * BK];   // 16 KB x3
  __shared__ __align__(16) u16 lsB[2][BN * BK];   // 32 KB x2  (112 KB total)
  const int tid = threadIdx.x;            // 0..511
  const int wave = tid >> 6, lane = tid & 63;
  const int lq = lane & 15, lr = lane >> 4;
  const int wr = wave >> 2, wc = wave & 3;
  const int m0 = blockIdx.y * BM, n0 = blockIdx.x * BN;

  auto stageA = [&](int t, int buf) {     // 2 loads/thread, 16 KB
    const int kt = t * BK;
    #pragma unroll
    for (int ii = 0; ii < 2; ++ii) {
      int s = ii * 512 + tid;             // 16B slot 0..1023
      int row = s >> 3, gq = (s & 7) ^ (row & 7);
      async16(xb + (size_t)(m0 + row) * EMB + kt + gq * 8, &lsA[buf][s * 8]);
    }
  };
  auto stageB = [&](int t, int buf, int half) {   // 2 loads/thread, 16 KB
    const int kt = t * BK;
    #pragma unroll
    for (int ii = 0; ii < 2; ++ii) {
      int s = ii * 512 + tid;
      int row = s >> 3, gq = (s & 7) ^ (row & 7);
      async16(wt + (size_t)(n0 + half * 128 + row) * EMB + kt + gq * 8,
              &lsB[buf][half * 8192 + s * 8]);
    }
  };

  f32x4 acc[4][4];
  #pragma unroll
  for (int i = 0; i < 4; ++i)
    #pragma unroll
    for (int j = 0; j < 4; ++j)
      acc[i][j] = f32x4{0.f, 0.f, 0.f, 0.f};

  // per-lane LDS read offsets (u16 units)
  int rbase[4];
  #pragma unroll
  for (int nf = 0; nf < 4; ++nf)
    rbase[nf] = ((wc >> 1) * 128 + (nf >> 1) * 64 + (wc & 1) * 32 + (nf & 1) * 16 + lq) * BK;
  const int aRow0 = (wr * 64 + lq) * BK;
  int qsw[2];
  qsw[0] = ((0 + lr) ^ (lq & 7)) * 8;
  qsw[1] = ((4 + lr) ^ (lq & 7)) * 8;

  // prologue: A0,B0,A1,B1 = 12 loads; vmcnt(6) -> oldest 6 = A0+B0 landed
  stageA(0, 0); stageB(0, 0, 0); stageB(0, 0, 1);
  stageA(1, 1); stageB(1, 1, 0); stageB(1, 1, 1);
  asm volatile("s_waitcnt vmcnt(6)" ::: "memory");
  GBAR();

  int pa = 0;                             // t % 3
  for (int t = 0; t < NT_K; ++t) {
    const u16* Ap = lsA[pa];
    const u16* Bp = lsB[t & 1];
    bf16x8 bfr[4][2];

    // ---------------- phase 0 ----------------
    #pragma unroll
    for (int nf = 0; nf < 4; ++nf)
      #pragma unroll
      for (int kk = 0; kk < 2; ++kk)
        bfr[nf][kk] = *(const bf16x8*)(Bp + rbase[nf] + qsw[kk]);
    bf16x8 af0[2][2];
    #pragma unroll
    for (int mfl = 0; mfl < 2; ++mfl)
      #pragma unroll
      for (int kk = 0; kk < 2; ++kk)
        af0[mfl][kk] = *(const bf16x8*)(Ap + aRow0 + (mfl * 16) * BK + qsw[kk]);

    if (t + 2 < NT_K) {
      int pa2 = pa + 2; if (pa2 >= 3) pa2 -= 3;
      stageA(t + 2, pa2);                 // lsA[(t+2)%3] drained at t-1.ph1 end
    }
    GBAR();
    WLGKM0();
    __builtin_amdgcn_s_setprio(1);
    #pragma unroll
    for (int kk = 0; kk < 2; ++kk)
      #pragma unroll
      for (int mfl = 0; mfl < 2; ++mfl)
        #pragma unroll
        for (int nf = 0; nf < 4; ++nf)
          acc[mfl][nf] = __builtin_amdgcn_mfma_f32_16x16x32_bf16(
              af0[mfl][kk], bfr[nf][kk], acc[mfl][nf], 0, 0, 0);
    __builtin_amdgcn_s_setprio(0);
    GBAR();

    // ---------------- phase 1 ----------------
    bf16x8 af1[2][2];
    #pragma unroll
    for (int mfl = 0; mfl < 2; ++mfl)
      #pragma unroll
      for (int kk = 0; kk < 2; ++kk)
        af1[mfl][kk] = *(const bf16x8*)(Ap + aRow0 + (32 + mfl * 16) * BK + qsw[kk]);

    if (t + 2 < NT_K) {
      stageB(t + 2, t & 1, 0);            // lsB[t&1] drained at t.ph0 end
      stageB(t + 2, t & 1, 1);
      asm volatile("s_waitcnt vmcnt(6)" ::: "memory");  // lands tile t+1 (A+B)
    } else if (t + 1 < NT_K) {
      asm volatile("s_waitcnt vmcnt(0)" ::: "memory");  // drain for last tile
    }
    GBAR();
    WLGKM0();
    __builtin_amdgcn_s_setprio(1);
    #pragma unroll
    for (int kk = 0; kk < 2; ++kk)
      #pragma unroll
      for (int mfl = 0; mfl < 2; ++mfl)
        #pragma unroll
        for (int nf = 0; nf < 4; ++nf)
          acc[2 + mfl][nf] = __builtin_amdgcn_mfma_f32_16x16x32_bf16(
              af1[mfl][kk], bfr[nf][kk], acc[2 + mfl][nf], 0, 0, 0);
    __builtin_amdgcn_s_setprio(0);
    GBAR();

    ++pa; if (pa >= 3) pa = 0;
  }

  // ---------------- epilogue (fused bias + RoPE / V-transpose) ----------------
  const int w = n0 >> 11;                  // 0=q, 1=k, 2=v (BN=256 divides 2048)
  const int h = ((n0 & 2047) >> 7) + (wc >> 1);
  float bb[4];
  int dloc[4];
  #pragma unroll
  for (int nf = 0; nf < 4; ++nf) {
    dloc[nf] = (nf >> 1) * 64 + (wc & 1) * 32 + (nf & 1) * 16 + lq;   // d within head
    bb[nf] = bias[n0 + (wc >> 1) * 128 + dloc[nf]];
  }

  if (w == 2) {
    // V: transpose to [B,H,D,SEQP], 4 consecutive s per 8B store
    #pragma unroll
    for (int mfg = 0; mfg < 4; ++mfg) {
      int mg0 = m0 + wr * 64 + mfg * 16 + lr * 4;
      int b = mg0 >> 11, s0 = mg0 & 2047;
      #pragma unroll
      for (int nf = 0; nf < 4; ++nf) {
        int d = dloc[nf];
        ushort4 pk;
        pk.x = f2bf(acc[mfg][nf][0] + bb[nf]);
        pk.y = f2bf(acc[mfg][nf][1] + bb[nf]);
        pk.z = f2bf(acc[mfg][nf][2] + bb[nf]);
        pk.w = f2bf(acc[mfg][nf][3] + bb[nf]);
        *(ushort4*)(vbt + ((size_t)(b * NH + h) * HD + d) * SEQP + s0) = pk;
      }
    }
  } else {
    u16* basep = (w == 0) ? qb : kb;
    const float qs = (w == 0) ? 0.12751569843736827f : 1.0f;  // log2(e)/sqrt(128) into q
    #pragma unroll
    for (int mfg = 0; mfg < 4; ++mfg)
      #pragma unroll
      for (int r = 0; r < 4; ++r) {
        int mg = m0 + wr * 64 + mfg * 16 + lr * 4 + r;
        int b = mg >> 11, s = mg & 2047;
        u16* dst = basep + ((size_t)(b * NH + h) * SEQ + s) * HD;
        #pragma unroll
        for (int nf = 0; nf < 2; ++nf) {
          int d1 = dloc[nf];                       // in [0,64); partner at d1+64
          float c1 = acc[mfg][nf][r]     + bb[nf];
          float c2 = acc[mfg][nf + 2][r] + bb[nf + 2];
          float2 s1 = tab[s * HD + d1];
          float2 s2 = tab[s * HD + d1 + 64];
          dst[d1]      = f2bf((c1 * s1.x - c2 * s1.y) * qs);
          dst[d1 + 64] = f2bf((c2 * s2.x + c1 * s2.y) * qs);
        }
      }
  }
}

// ---------------- flash attention (unchanged; round-4 structure + XCD-aware remap) ----------------
__global__ __launch_bounds__(128, 2) void k_flash(
    const u16* __restrict__ qb, const u16* __restrict__ kb,
    const u16* __restrict__ vbt, float* __restrict__ out)
{
  __shared__ __align__(16) u16 lsK[2][KT * HD];   // [key][d] 16B-grp ^= key&7    (8 KB x2)
  __shared__ __align__(16) u16 lsV[2][HD * KT];   // [d][key] 16B-grp ^= (d>>1)&3 (8 KB x2)
  __shared__ __align__(16) u16 lsP[2][WQ * KT];   // per-wave [qrow][key], 8B-grp ^= row&6

  const int tid = threadIdx.x;            // 0..127
  const int wave = tid >> 6, lane = tid & 63;
  const int lq = lane & 15, lr = lane >> 4;
  const int i = blockIdx.x;               // 0..1023
  const int xcd = i & 7, j = i >> 3;      // j: 0..127
  const int bh = xcd * 4 + (j >> 5);      // 4 heads per XCD
  const int q0 = (j & 31) * QT;
  const u16* Qg = qb + ((size_t)bh * SEQ + q0 + wave * WQ) * HD;
  const u16* Kg = kb + (size_t)bh * SEQ * HD;
  const u16* Vg = vbt + (size_t)bh * HD * SEQP;

  auto stage = [&](int tile, int buf) {
    const int k0 = tile * KT;
    #pragma unroll
    for (int ii = 0; ii < 4; ++ii) {
      int c = tid + ii * 128;
      int key = c >> 4, grp = c & 15;
      async16(Kg + (size_t)(k0 + key) * HD + ((grp ^ (key & 7)) * 8), lsK[buf] + c * 8);
    }
    #pragma unroll
    for (int ii = 0; ii < 4; ++ii) {
      int c = tid + ii * 128;
      int d = c >> 2, g2 = c & 3;
      async16(Vg + (size_t)d * SEQP + k0 + ((g2 ^ ((d >> 1) & 3)) * 8), lsV[buf] + c * 8);
    }
  };

  stage(0, 0);

  bf16x8 qf[2][4];
  #pragma unroll
  for (int qq = 0; qq < 2; ++qq)
    #pragma unroll
    for (int ks = 0; ks < 4; ++ks)
      qf[qq][ks] = *(const bf16x8*)(Qg + (size_t)(qq * 16 + lq) * HD + ks * 32 + lr * 8);

  f32x4 acc_o[2][8];
  float lsum[2] = {0.f, 0.f};
  #pragma unroll
  for (int mb = 0; mb < 2; ++mb)
    #pragma unroll
    for (int nb = 0; nb < 8; ++nb) acc_o[mb][nb] = f32x4{0.f, 0.f, 0.f, 0.f};

  for (int t = 0; t < NTILE; ++t) {
    const int p = t & 1;
    __syncthreads();                 // drains stage(t); all waves done with buf 1-p
    if (t + 1 < NTILE) stage(t + 1, 1 - p);

    // S^T = K Q^T : 32 keys x 32 q-rows per wave
    f32x4 sacc[2][2];
    #pragma unroll
    for (int kbi = 0; kbi < 2; ++kbi)
      #pragma unroll
      for (int qq = 0; qq < 2; ++qq) sacc[kbi][qq] = f32x4{0.f, 0.f, 0.f, 0.f};
    #pragma unroll
    for (int ks = 0; ks < 4; ++ks) {
      bf16x8 kf[2];
      #pragma unroll
      for (int kbi = 0; kbi < 2; ++kbi) {
        int key = kbi * 16 + lq;
        int g = (ks * 4 + lr) ^ (key & 7);
        kf[kbi] = *(const bf16x8*)(lsK[p] + key * HD + g * 8);
      }
      #pragma unroll
      for (int kbi = 0; kbi < 2; ++kbi)
        #pragma unroll
        for (int qq = 0; qq < 2; ++qq)
          sacc[kbi][qq] = __builtin_amdgcn_mfma_f32_16x16x32_bf16(kf[kbi], qf[qq][ks], sacc[kbi][qq], 0, 0, 0);
    }

    // P = exp2(S) (log2e folded into q); packed b64 writes (4 consecutive keys/lane)
    #pragma unroll
    for (int kbi = 0; kbi < 2; ++kbi)
      #pragma unroll
      for (int qq = 0; qq < 2; ++qq) {
        float p0 = __builtin_amdgcn_exp2f(sacc[kbi][qq][0]);
        float p1 = __builtin_amdgcn_exp2f(sacc[kbi][qq][1]);
        float p2 = __builtin_amdgcn_exp2f(sacc[kbi][qq][2]);
        float p3 = __builtin_amdgcn_exp2f(sacc[kbi][qq][3]);
        lsum[qq] += (p0 + p1) + (p2 + p3);
        int row = qq * 16 + lq;
        int g = kbi * 4 + lr;
        int gp = g ^ (row & 6);
        uint2 pk;
        pk.x = (uint32_t)f2bf(p0) | ((uint32_t)f2bf(p1) << 16);
        pk.y = (uint32_t)f2bf(p2) | ((uint32_t)f2bf(p3) << 16);
        *(uint2*)(lsP[wave] + row * KT + gp * 4) = pk;
      }

    // O += P V
    bf16x8 ap[2];
    #pragma unroll
    for (int mb = 0; mb < 2; ++mb) {
      int row = mb * 16 + lq;
      int gp = (2 * lr) ^ (row & 6);
      ap[mb] = *(const bf16x8*)(lsP[wave] + row * KT + gp * 4);
    }
    #pragma unroll
    for (int nb = 0; nb < 8; ++nb) {
      int d = nb * 16 + lq;
      int g2 = lr ^ ((d >> 1) & 3);
      bf16x8 bv = *(const bf16x8*)(lsV[p] + d * KT + g2 * 8);
      #pragma unroll
      for (int mb = 0; mb < 2; ++mb)
        acc_o[mb][nb] = __builtin_amdgcn_mfma_f32_16x16x32_bf16(ap[mb], bv[0] == bv[0] ? bv : bv, acc_o[mb][nb], 0, 0, 0);
    }
  }

  float inv[2];
  #pragma unroll
  for (int qq = 0; qq < 2; ++qq) {
    float s = lsum[qq];
    s += __shfl_xor(s, 16);
    s += __shfl_xor(s, 32);
    inv[qq] = 1.0f / s;
  }
  const int b = bh >> 4, h = bh & 15;
  #pragma unroll
  for (int mb = 0; mb < 2; ++mb)
    #pragma unroll
    for (int r = 0; r < 4; ++r) {
      float iv = __shfl(inv[mb], lr * 4 + r);
      int row = wave * WQ + mb * 16 + lr * 4 + r;
      int sq = q0 + row;
      float* op = out + (((size_t)b * SEQ + sq) * NH + h) * HD;
      #pragma unroll
      for (int nb = 0; nb < 8; ++nb)
        op[nb * 16 + lq] = acc_o[mb][nb][r] * iv;
    }
}

// ---------------- launch ----------------

extern "C" void kernel_launch(void* const* d_in, const int* in_sizes, int n_in,
                              void* d_out, int out_size, void* d_ws, size_t ws_size,
                              hipStream_t stream) {
  (void)in_sizes; (void)n_in; (void)out_size; (void)ws_size;
  const float* x    = (const float*)d_in[0];
  const float* W    = (const float*)d_in[1];
  const float* bias = (const float*)d_in[2];
  float* out = (float*)d_out;

  char* p = (char*)d_ws;
  u16* xb  = (u16*)p;  p += (size_t)MM * EMB * 2;                     // 16.8 MB
  u16* wt  = (u16*)p;  p += (size_t)N3 * EMB * 2;                     // 25.2 MB
  u16* qb  = (u16*)p;  p += (size_t)NUM_B * NH * SEQ * HD * 2;        // 16.8 MB
  u16* kb  = (u16*)p;  p += (size_t)NUM_B * NH * SEQ * HD * 2;        // 16.8 MB
  u16* vbt = (u16*)p;  p += (size_t)NUM_B * NH * HD * SEQP * 2;       // 17.0 MB
  float2* tab = (float2*)p;                                           // 2.1 MB

  k_cvt_bf16<<<(MM * EMB / 4 + 255) / 256, 256, 0, stream>>>(x, xb, MM * EMB / 4);
  k_transpose_w<<<dim3(N3 / 32, EMB / 32), dim3(32, 8), 0, stream>>>(W, wt);
  k_sincos<<<(SEQ * HD) / 256, 256, 0, stream>>>(tab);
  k_gemm_qkv<<<dim3(N3 / BN, MM / BM), 512, 0, stream>>>(xb, wt, bias, tab, qb, kb, vbt);
  k_flash<<<SEQ / QT * NUM_B * NH, 128, 0, stream>>>(qb, kb, vbt, out);
}

// Round 3
// 257.710 us; speedup vs baseline: 1.0125x; 1.0125x over previous
//
#include <hip/hip_runtime.h>
#include <stdint.h>

typedef unsigned short u16;
typedef __attribute__((ext_vector_type(8))) short bf16x8;   // 8 bf16 = 4 VGPRs
typedef __attribute__((ext_vector_type(4))) float f32x4;

#define NUM_B 2
#define SEQ   2048
#define SEQP  2080      // padded V row stride
#define NH    16
#define HD    128
#define EMB   2048      // NH*HD
#define N3    6144      // 3*EMB
#define MM    4096      // NUM_B*SEQ
#define QT    64        // flash q-rows per block (2 waves)
#define WQ    32        // flash q-rows per wave
#define KT    32        // flash keys per k-tile
#define NTILE (SEQ / KT)

// ---- GEMM tile params ----
#define BM 128
#define BN 256
#define BK 64
#define NT_K (EMB / BK)   // 32 K-tiles

__device__ __forceinline__ u16 f2bf(float f) {
  union { float f; unsigned u; } c; c.f = f;
  return (u16)((c.u + 0x7FFFu + ((c.u >> 16) & 1u)) >> 16);   // RNE
}
__device__ __forceinline__ void async16(const void* g, void* l) {
  __builtin_amdgcn_global_load_lds(
      (const __attribute__((address_space(1))) void*)g,
      (__attribute__((address_space(3))) void*)l, 16, 0, 0);
}

#define GBAR()   asm volatile("s_barrier" ::: "memory")
#define WLGKM0() asm volatile("s_waitcnt lgkmcnt(0)" ::: "memory")

// ---------------- prep kernels ----------------

__global__ void k_cvt_bf16(const float* __restrict__ in, u16* __restrict__ out, int n4) {
  int i = blockIdx.x * blockDim.x + threadIdx.x;
  if (i >= n4) return;
  const float4 v = ((const float4*)in)[i];
  ushort4 o;
  o.x = f2bf(v.x); o.y = f2bf(v.y); o.z = f2bf(v.z); o.w = f2bf(v.w);
  ((ushort4*)out)[i] = o;
}

// W [EMB][N3] fp32 -> Wt [N3][EMB] bf16
__global__ void k_transpose_w(const float* __restrict__ W, u16* __restrict__ Wt) {
  __shared__ float t[32][33];
  int n0 = blockIdx.x * 32, k0 = blockIdx.y * 32;
  int tx = threadIdx.x, ty = threadIdx.y;
  #pragma unroll
  for (int i = ty; i < 32; i += 8)
    t[i][tx] = W[(size_t)(k0 + i) * N3 + n0 + tx];
  __syncthreads();
  #pragma unroll
  for (int i = ty; i < 32; i += 8)
    Wt[(size_t)(n0 + i) * EMB + k0 + tx] = f2bf(t[tx][i]);
}

// sincos table for t = s*HD + d; double-precision sincos matches numpy fp32 tables
__global__ void k_sincos(float2* __restrict__ tab) {
  int i = blockIdx.x * blockDim.x + threadIdx.x;   // 0 .. SEQ*HD-1
  double t = (double)i;
  tab[i] = make_float2((float)cos(t), (float)sin(t));
}

// ---------------- QKV GEMM: 128x256, BK=64, 8 waves, BALANCED 2-phase ----------------
// R2 post-mortem: ph0 had 12/16 of the ds_reads before its lgkmcnt(0) gate
// (~1150 cyc LDS burst vs 620 cyc MFMA) -> waves camped at the gate, 27% util.
// Fix: split phases on kk (the K-halves of the tile), not on m:
//  ph0: ds_read kk=0 frags (4 A + 4 B b128); issue stageA(t+2); barrier;
//       lgkmcnt(0); setprio(1); 16 MFMA (all mfg x nf, kk=0); setprio(0); barrier
//  ph1: ds_read kk=1 frags (4 A + 4 B); issue stageB(t+2); vmcnt(6); barrier;
//       lgkmcnt(0); setprio(1); 16 MFMA (kk=1); setprio(0); barrier
// Per phase per CU: 64 b128 (~770 cyc) vs 620 cyc MFMA -> balanced; wave skew
// lets LDS retire reads under MFMA. Accumulation order kk0->kk1 per element is
// unchanged -> bit-identical numerics.
// B is now read in BOTH phases, so stageB(t+2) in ph1 must not target a live
// buffer -> B triple-buffered like A (target (t+2)%3 fully drained at tile
// t-1's end barrier). LDS = 3*16 + 3*32 = 144 KB, 1 block/CU.
// vmcnt(6): outstanding at wait = A(t+1)[2] B(t+1)[4] A(t+2)[2] B(t+2)[4];
// waits oldest 6 = all of tile t+1, keeps tile t+2 (6 loads) in flight.
// LDS swizzle (T2, verified 0-conflict in R1/R2): slot quad = quad ^ (row&7),
// applied to per-lane GLOBAL source (dest linear) and to the ds_read quad.
__global__ __launch_bounds__(512, 2) void k_gemm_qkv(
    const u16* __restrict__ xb, const u16* __restrict__ wt,
    const float* __restrict__ bias, const float2* __restrict__ tab,
    u16* __restrict__ qb, u16* __restrict__ kb, u16* __restrict__ vbt)
{
  __shared__ __align__(16) u16 lsA[3][BM * BK];   // 16 KB x3
  __shared__ __align__(16) u16 lsB[3][BN * BK];   // 32 KB x3  (144 KB total)
  const int tid = threadIdx.x;            // 0..511
  const int wave = tid >> 6, lane = tid & 63;
  const int lq = lane & 15, lr = lane >> 4;
  const int wr = wave >> 2, wc = wave & 3;
  const int m0 = blockIdx.y * BM, n0 = blockIdx.x * BN;

  auto stageA = [&](int t, int buf) {     // 2 loads/thread, 16 KB
    const int kt = t * BK;
    #pragma unroll
    for (int ii = 0; ii < 2; ++ii) {
      int s = ii * 512 + tid;             // 16B slot 0..1023
      int row = s >> 3, gq = (s & 7) ^ (row & 7);
      async16(xb + (size_t)(m0 + row) * EMB + kt + gq * 8, &lsA[buf][s * 8]);
    }
  };
  auto stageB = [&](int t, int buf, int half) {   // 2 loads/thread, 16 KB
    const int kt = t * BK;
    #pragma unroll
    for (int ii = 0; ii < 2; ++ii) {
      int s = ii * 512 + tid;
      int row = s >> 3, gq = (s & 7) ^ (row & 7);
      async16(wt + (size_t)(n0 + half * 128 + row) * EMB + kt + gq * 8,
              &lsB[buf][half * 8192 + s * 8]);
    }
  };

  f32x4 acc[4][4];
  #pragma unroll
  for (int i = 0; i < 4; ++i)
    #pragma unroll
    for (int j = 0; j < 4; ++j)
      acc[i][j] = f32x4{0.f, 0.f, 0.f, 0.f};

  // per-lane LDS read offsets (u16 units)
  int rbase[4];
  #pragma unroll
  for (int nf = 0; nf < 4; ++nf)
    rbase[nf] = ((wc >> 1) * 128 + (nf >> 1) * 64 + (wc & 1) * 32 + (nf & 1) * 16 + lq) * BK;
  const int aRow0 = (wr * 64 + lq) * BK;
  int qsw[2];
  qsw[0] = ((0 + lr) ^ (lq & 7)) * 8;
  qsw[1] = ((4 + lr) ^ (lq & 7)) * 8;

  // prologue: A0,B0,A1,B1 = 12 loads; vmcnt(6) -> oldest 6 = A0+B0 landed
  stageA(0, 0); stageB(0, 0, 0); stageB(0, 0, 1);
  stageA(1, 1); stageB(1, 1, 0); stageB(1, 1, 1);
  asm volatile("s_waitcnt vmcnt(6)" ::: "memory");
  GBAR();

  int pa = 0;                             // t % 3
  for (int t = 0; t < NT_K; ++t) {
    const u16* Ap = lsA[pa];
    const u16* Bp = lsB[pa];
    int pa2 = pa + 2; if (pa2 >= 3) pa2 -= 3;

    // ---------------- phase 0 : kk = 0 ----------------
    bf16x8 af0[4], bf0[4];
    #pragma unroll
    for (int nf = 0; nf < 4; ++nf)
      bf0[nf] = *(const bf16x8*)(Bp + rbase[nf] + qsw[0]);
    #pragma unroll
    for (int mfg = 0; mfg < 4; ++mfg)
      af0[mfg] = *(const bf16x8*)(Ap + aRow0 + (mfg * 16) * BK + qsw[0]);

    if (t + 2 < NT_K) stageA(t + 2, pa2);   // lsA[(t+2)%3] drained at t-1.ph1 end
    GBAR();
    WLGKM0();
    __builtin_amdgcn_s_setprio(1);
    #pragma unroll
    for (int mfg = 0; mfg < 4; ++mfg)
      #pragma unroll
      for (int nf = 0; nf < 4; ++nf)
        acc[mfg][nf] = __builtin_amdgcn_mfma_f32_16x16x32_bf16(
            af0[mfg], bf0[nf], acc[mfg][nf], 0, 0, 0);
    __builtin_amdgcn_s_setprio(0);
    GBAR();

    // ---------------- phase 1 : kk = 1 ----------------
    bf16x8 af1[4], bf1[4];
    #pragma unroll
    for (int nf = 0; nf < 4; ++nf)
      bf1[nf] = *(const bf16x8*)(Bp + rbase[nf] + qsw[1]);
    #pragma unroll
    for (int mfg = 0; mfg < 4; ++mfg)
      af1[mfg] = *(const bf16x8*)(Ap + aRow0 + (mfg * 16) * BK + qsw[1]);

    if (t + 2 < NT_K) {
      stageB(t + 2, pa2, 0);               // lsB[(t+2)%3] drained at t-1.ph1 end
      stageB(t + 2, pa2, 1);
      asm volatile("s_waitcnt vmcnt(6)" ::: "memory");  // lands tile t+1 (A+B)
    } else if (t + 1 < NT_K) {
      asm volatile("s_waitcnt vmcnt(0)" ::: "memory");  // drain for last tile
    }
    GBAR();
    WLGKM0();
    __builtin_amdgcn_s_setprio(1);
    #pragma unroll
    for (int mfg = 0; mfg < 4; ++mfg)
      #pragma unroll
      for (int nf = 0; nf < 4; ++nf)
        acc[mfg][nf] = __builtin_amdgcn_mfma_f32_16x16x32_bf16(
            af1[mfg], bf1[nf], acc[mfg][nf], 0, 0, 0);
    __builtin_amdgcn_s_setprio(0);
    GBAR();

    ++pa; if (pa >= 3) pa = 0;
  }

  // ---------------- epilogue (fused bias + RoPE / V-transpose) ----------------
  const int w = n0 >> 11;                  // 0=q, 1=k, 2=v (BN=256 divides 2048)
  const int h = ((n0 & 2047) >> 7) + (wc >> 1);
  float bb[4];
  int dloc[4];
  #pragma unroll
  for (int nf = 0; nf < 4; ++nf) {
    dloc[nf] = (nf >> 1) * 64 + (wc & 1) * 32 + (nf & 1) * 16 + lq;   // d within head
    bb[nf] = bias[n0 + (wc >> 1) * 128 + dloc[nf]];
  }

  if (w == 2) {
    // V: transpose to [B,H,D,SEQP], 4 consecutive s per 8B store
    #pragma unroll
    for (int mfg = 0; mfg < 4; ++mfg) {
      int mg0 = m0 + wr * 64 + mfg * 16 + lr * 4;
      int b = mg0 >> 11, s0 = mg0 & 2047;
      #pragma unroll
      for (int nf = 0; nf < 4; ++nf) {
        int d = dloc[nf];
        ushort4 pk;
        pk.x = f2bf(acc[mfg][nf][0] + bb[nf]);
        pk.y = f2bf(acc[mfg][nf][1] + bb[nf]);
        pk.z = f2bf(acc[mfg][nf][2] + bb[nf]);
        pk.w = f2bf(acc[mfg][nf][3] + bb[nf]);
        *(ushort4*)(vbt + ((size_t)(b * NH + h) * HD + d) * SEQP + s0) = pk;
      }
    }
  } else {
    u16* basep = (w == 0) ? qb : kb;
    const float qs = (w == 0) ? 0.12751569843736827f : 1.0f;  // log2(e)/sqrt(128) into q
    #pragma unroll
    for (int mfg = 0; mfg < 4; ++mfg)
      #pragma unroll
      for (int r = 0; r < 4; ++r) {
        int mg = m0 + wr * 64 + mfg * 16 + lr * 4 + r;
        int b = mg >> 11, s = mg & 2047;
        u16* dst = basep + ((size_t)(b * NH + h) * SEQ + s) * HD;
        #pragma unroll
        for (int nf = 0; nf < 2; ++nf) {
          int d1 = dloc[nf];                       // in [0,64); partner at d1+64
          float c1 = acc[mfg][nf][r]     + bb[nf];
          float c2 = acc[mfg][nf + 2][r] + bb[nf + 2];
          float2 s1 = tab[s * HD + d1];
          float2 s2 = tab[s * HD + d1 + 64];
          dst[d1]      = f2bf((c1 * s1.x - c2 * s1.y) * qs);
          dst[d1 + 64] = f2bf((c2 * s2.x + c1 * s2.y) * qs);
        }
      }
  }
}

// ---------------- flash attention (unchanged; round-4 structure + XCD-aware remap) ----------------
__global__ __launch_bounds__(128, 2) void k_flash(
    const u16* __restrict__ qb, const u16* __restrict__ kb,
    const u16* __restrict__ vbt, float* __restrict__ out)
{
  __shared__ __align__(16) u16 lsK[2][KT * HD];   // [key][d] 16B-grp ^= key&7    (8 KB x2)
  __shared__ __align__(16) u16 lsV[2][HD * KT];   // [d][key] 16B-grp ^= (d>>1)&3 (8 KB x2)
  __shared__ __align__(16) u16 lsP[2][WQ * KT];   // per-wave [qrow][key], 8B-grp ^= row&6

  const int tid = threadIdx.x;            // 0..127
  const int wave = tid >> 6, lane = tid & 63;
  const int lq = lane & 15, lr = lane >> 4;
  const int i = blockIdx.x;               // 0..1023
  const int xcd = i & 7, j = i >> 3;      // j: 0..127
  const int bh = xcd * 4 + (j >> 5);      // 4 heads per XCD
  const int q0 = (j & 31) * QT;
  const u16* Qg = qb + ((size_t)bh * SEQ + q0 + wave * WQ) * HD;
  const u16* Kg = kb + (size_t)bh * SEQ * HD;
  const u16* Vg = vbt + (size_t)bh * HD * SEQP;

  auto stage = [&](int tile, int buf) {
    const int k0 = tile * KT;
    #pragma unroll
    for (int ii = 0; ii < 4; ++ii) {
      int c = tid + ii * 128;
      int key = c >> 4, grp = c & 15;
      async16(Kg + (size_t)(k0 + key) * HD + ((grp ^ (key & 7)) * 8), lsK[buf] + c * 8);
    }
    #pragma unroll
    for (int ii = 0; ii < 4; ++ii) {
      int c = tid + ii * 128;
      int d = c >> 2, g2 = c & 3;
      async16(Vg + (size_t)d * SEQP + k0 + ((g2 ^ ((d >> 1) & 3)) * 8), lsV[buf] + c * 8);
    }
  };

  stage(0, 0);

  bf16x8 qf[2][4];
  #pragma unroll
  for (int qq = 0; qq < 2; ++qq)
    #pragma unroll
    for (int ks = 0; ks < 4; ++ks)
      qf[qq][ks] = *(const bf16x8*)(Qg + (size_t)(qq * 16 + lq) * HD + ks * 32 + lr * 8);

  f32x4 acc_o[2][8];
  float lsum[2] = {0.f, 0.f};
  #pragma unroll
  for (int mb = 0; mb < 2; ++mb)
    #pragma unroll
    for (int nb = 0; nb < 8; ++nb) acc_o[mb][nb] = f32x4{0.f, 0.f, 0.f, 0.f};

  for (int t = 0; t < NTILE; ++t) {
    const int p = t & 1;
    __syncthreads();                 // drains stage(t); all waves done with buf 1-p
    if (t + 1 < NTILE) stage(t + 1, 1 - p);

    // S^T = K Q^T : 32 keys x 32 q-rows per wave
    f32x4 sacc[2][2];
    #pragma unroll
    for (int kbi = 0; kbi < 2; ++kbi)
      #pragma unroll
      for (int qq = 0; qq < 2; ++qq) sacc[kbi][qq] = f32x4{0.f, 0.f, 0.f, 0.f};
    #pragma unroll
    for (int ks = 0; ks < 4; ++ks) {
      bf16x8 kf[2];
      #pragma unroll
      for (int kbi = 0; kbi < 2; ++kbi) {
        int key = kbi * 16 + lq;
        int g = (ks * 4 + lr) ^ (key & 7);
        kf[kbi] = *(const bf16x8*)(lsK[p] + key * HD + g * 8);
      }
      #pragma unroll
      for (int kbi = 0; kbi < 2; ++kbi)
        #pragma unroll
        for (int qq = 0; qq < 2; ++qq)
          sacc[kbi][qq] = __builtin_amdgcn_mfma_f32_16x16x32_bf16(kf[kbi], qf[qq][ks], sacc[kbi][qq], 0, 0, 0);
    }

    // P = exp2(S) (log2e folded into q); packed b64 writes (4 consecutive keys/lane)
    #pragma unroll
    for (int kbi = 0; kbi < 2; ++kbi)
      #pragma unroll
      for (int qq = 0; qq < 2; ++qq) {
        float p0 = __builtin_amdgcn_exp2f(sacc[kbi][qq][0]);
        float p1 = __builtin_amdgcn_exp2f(sacc[kbi][qq][1]);
        float p2 = __builtin_amdgcn_exp2f(sacc[kbi][qq][2]);
        float p3 = __builtin_amdgcn_exp2f(sacc[kbi][qq][3]);
        lsum[qq] += (p0 + p1) + (p2 + p3);
        int row = qq * 16 + lq;
        int g = kbi * 4 + lr;
        int gp = g ^ (row & 6);
        uint2 pk;
        pk.x = (uint32_t)f2bf(p0) | ((uint32_t)f2bf(p1) << 16);
        pk.y = (uint32_t)f2bf(p2) | ((uint32_t)f2bf(p3) << 16);
        *(uint2*)(lsP[wave] + row * KT + gp * 4) = pk;
      }

    // O += P V
    bf16x8 ap[2];
    #pragma unroll
    for (int mb = 0; mb < 2; ++mb) {
      int row = mb * 16 + lq;
      int gp = (2 * lr) ^ (row & 6);
      ap[mb] = *(const bf16x8*)(lsP[wave] + row * KT + gp * 4);
    }
    #pragma unroll
    for (int nb = 0; nb < 8; ++nb) {
      int d = nb * 16 + lq;
      int g2 = lr ^ ((d >> 1) & 3);
      bf16x8 bv = *(const bf16x8*)(lsV[p] + d * KT + g2 * 8);
      #pragma unroll
      for (int mb = 0; mb < 2; ++mb)
        acc_o[mb][nb] = __builtin_amdgcn_mfma_f32_16x16x32_bf16(ap[mb], bv[0] == bv[0] ? bv : bv, acc_o[mb][nb], 0, 0, 0);
    }
  }

  float inv[2];
  #pragma unroll
  for (int qq = 0; qq < 2; ++qq) {
    float s = lsum[qq];
    s += __shfl_xor(s, 16);
    s += __shfl_xor(s, 32);
    inv[qq] = 1.0f / s;
  }
  const int b = bh >> 4, h = bh & 15;
  #pragma unroll
  for (int mb = 0; mb < 2; ++mb)
    #pragma unroll
    for (int r = 0; r < 4; ++r) {
      float iv = __shfl(inv[mb], lr * 4 + r);
      int row = wave * WQ + mb * 16 + lr * 4 + r;
      int sq = q0 + row;
      float* op = out + (((size_t)b * SEQ + sq) * NH + h) * HD;
      #pragma unroll
      for (int nb = 0; nb < 8; ++nb)
        op[nb * 16 + lq] = acc_o[mb][nb][r] * iv;
    }
}

// ---------------- launch ----------------

extern "C" void kernel_launch(void* const* d_in, const int* in_sizes, int n_in,
                              void* d_out, int out_size, void* d_ws, size_t ws_size,
                              hipStream_t stream) {
  (void)in_sizes; (void)n_in; (void)out_size; (void)ws_size;
  const float* x    = (const float*)d_in[0];
  const float* W    = (const float*)d_in[1];
  const float* bias = (const float*)d_in[2];
  float* out = (float*)d_out;

  char* p = (char*)d_ws;
  u16* xb  = (u16*)p;  p += (size_t)MM * EMB * 2;                     // 16.8 MB
  u16* wt  = (u16*)p;  p += (size_t)N3 * EMB * 2;                     // 25.2 MB
  u16* qb  = (u16*)p;  p += (size_t)NUM_B * NH * SEQ * HD * 2;        // 16.8 MB
  u16* kb  = (u16*)p;  p += (size_t)NUM_B * NH * SEQ * HD * 2;        // 16.8 MB
  u16* vbt = (u16*)p;  p += (size_t)NUM_B * NH * HD * SEQP * 2;       // 17.0 MB
  float2* tab = (float2*)p;                                           // 2.1 MB

  k_cvt_bf16<<<(MM * EMB / 4 + 255) / 256, 256, 0, stream>>>(x, xb, MM * EMB / 4);
  k_transpose_w<<<dim3(N3 / 32, EMB / 32), dim3(32, 8), 0, stream>>>(W, wt);
  k_sincos<<<(SEQ * HD) / 256, 256, 0, stream>>>(tab);
  k_gemm_qkv<<<dim3(N3 / BN, MM / BM), 512, 0, stream>>>(xb, wt, bias, tab, qb, kb, vbt);
  k_flash<<<SEQ / QT * NUM_B * NH, 128, 0, stream>>>(qb, kb, vbt, out);
}

// Round 4
// 245.751 us; speedup vs baseline: 1.0618x; 1.0487x over previous
//
#include <hip/hip_runtime.h>
#include <stdint.h>

typedef unsigned short u16;
typedef __attribute__((ext_vector_type(8))) short bf16x8;   // 8 bf16 = 4 VGPRs
typedef __attribute__((ext_vector_type(4))) float f32x4;

#define NUM_B 2
#define SEQ   2048
#define SEQP  2080      // padded V row stride
#define NH    16
#define HD    128
#define EMB   2048      // NH*HD
#define N3    6144      // 3*EMB
#define MM    4096      // NUM_B*SEQ
#define QT    64        // flash q-rows per block (2 waves)
#define WQ    32        // flash q-rows per wave
#define KT    32        // flash keys per k-tile
#define NTILE (SEQ / KT)

// ---- GEMM tile params: m201-geometry 256x256, BK=64, 8 waves ----
#define BM 256
#define BN 256
#define BK 64
#define NT_K (EMB / BK)   // 32 K-tiles, 16 iterations of 2

__device__ __forceinline__ u16 f2bf(float f) {
  union { float f; unsigned u; } c; c.f = f;
  return (u16)((c.u + 0x7FFFu + ((c.u >> 16) & 1u)) >> 16);   // RNE
}
__device__ __forceinline__ void async16(const void* g, void* l) {
  __builtin_amdgcn_global_load_lds(
      (const __attribute__((address_space(1))) void*)g,
      (__attribute__((address_space(3))) void*)l, 16, 0, 0);
}

#define GBAR()   asm volatile("s_barrier" ::: "memory")
#define WLGKM0() asm volatile("s_waitcnt lgkmcnt(0)" ::: "memory")

// ---------------- prep kernels ----------------

__global__ void k_cvt_bf16(const float* __restrict__ in, u16* __restrict__ out, int n4) {
  int i = blockIdx.x * blockDim.x + threadIdx.x;
  if (i >= n4) return;
  const float4 v = ((const float4*)in)[i];
  ushort4 o;
  o.x = f2bf(v.x); o.y = f2bf(v.y); o.z = f2bf(v.z); o.w = f2bf(v.w);
  ((ushort4*)out)[i] = o;
}

// W [EMB][N3] fp32 -> Wt [N3][EMB] bf16
__global__ void k_transpose_w(const float* __restrict__ W, u16* __restrict__ Wt) {
  __shared__ float t[32][33];
  int n0 = blockIdx.x * 32, k0 = blockIdx.y * 32;
  int tx = threadIdx.x, ty = threadIdx.y;
  #pragma unroll
  for (int i = ty; i < 32; i += 8)
    t[i][tx] = W[(size_t)(k0 + i) * N3 + n0 + tx];
  __syncthreads();
  #pragma unroll
  for (int i = ty; i < 32; i += 8)
    Wt[(size_t)(n0 + i) * EMB + k0 + tx] = f2bf(t[tx][i]);
}

// sincos table for t = s*HD + d; double-precision sincos matches numpy fp32 tables
__global__ void k_sincos(float2* __restrict__ tab) {
  int i = blockIdx.x * blockDim.x + threadIdx.x;   // 0 .. SEQ*HD-1
  double t = (double)i;
  tab[i] = make_float2((float)cos(t), (float)sin(t));
}

// ---------------- QKV GEMM: 256x256 8-phase template (m201 geometry) ----------------
// R3 post-mortem: 64x64/wave tiles are LDS-read-bound (0.5 b128/MFMA); three
// schedules all pinned at ~28% MfmaUtil. Fix = per-wave 128x64 (0.375 b128/MFMA)
// with the proven 8-phase counted-vmcnt schedule.
// Geometry: 8 waves = 2(M-half wr) x 4(N-quarter wc); per-wave C = 8mf x 4nf
// 16x16 frags; acc[8][4]. LDS: lsA[2][256*64], lsB[2][256*64] = 128 KB; even
// K-tiles -> buf0, odd -> buf1 (static). Iteration = 2 K-tiles (t0,t1), 8 phases:
//   P1..P4 = tile t0 quadrants q (mf=2q,2q+1): ds_read 4 A b128 (+8 B b128 at
//   q==0); P5..P8 same for t1. Each phase stages ONE half-tile (2 async16/thr):
//     P1: A(t1)h0   P2: A(t1)h1   P3: B(t0+2)h0  P4: B(t0+2)h1 + vmcnt(4)
//     P5: A(t0+2)h0 P6: A(t0+2)h1 P7: B(t1+2)h0  P8: B(t1+2)h1 + vmcnt(4)
//   (every stage target's last ds_read retired >=1 phase-end-barrier earlier)
//   vmcnt(4): at P4 queue = B(t1)[4] A(t1)[4] B(t0+2)[4] -> lands B(t1)+A(t1)
//   before P5 reads them; at P8 queue = B(t0+2) A(t0+2) B(t1+2) -> lands tile
//   t0+2 before next-iter P1. Never 0 in steady state.
//   Phase: reads; stage; [lgkmcnt(8) on 12-read phases]; barrier; lgkmcnt(0);
//   setprio(1); 16 MFMA; setprio(0); barrier.
// Swizzle (T2, 0-conflict verified R1-R3): slot quad = quad ^ (row&7), applied
// to per-lane GLOBAL source (LDS dest linear) and to the ds_read quad; all
// fragment rows have row&7 == lq&7 so qsw[kk] = ((kk*4+lr)^(lq&7))*8 is shared.
// RoPE-pair N-remap: wave wc, frag nf -> within-head d = (2*(wc&1)+(nf>>1))*16
// + (nf&1)*64 + lq, head = wc>>1. Pairs (nf=2pl, 2pl+1) give (d, d+64) in-wave;
// bijective over the 256 cols.
__global__ __launch_bounds__(512, 2) void k_gemm_qkv(
    const u16* __restrict__ xb, const u16* __restrict__ wt,
    const float* __restrict__ bias, const float2* __restrict__ tab,
    u16* __restrict__ qb, u16* __restrict__ kb, u16* __restrict__ vbt)
{
  __shared__ __align__(16) u16 lsA[2][BM * BK];   // 32 KB x2
  __shared__ __align__(16) u16 lsB[2][BN * BK];   // 32 KB x2  (128 KB total)
  const int tid = threadIdx.x;            // 0..511
  const int wave = tid >> 6, lane = tid & 63;
  const int lq = lane & 15, lr = lane >> 4;
  const int wr = wave >> 2, wc = wave & 3;
  const int m0 = blockIdx.y * BM, n0 = blockIdx.x * BN;

  auto stA = [&](int t, int half) {       // one half-tile: 2 loads/thread, 16 KB
    const int kt = t * BK;
    #pragma unroll
    for (int ii = 0; ii < 2; ++ii) {
      int s = ii * 512 + tid;             // 16B slot 0..1023 within half
      int row = s >> 3, gq = (s & 7) ^ (row & 7);
      async16(xb + (size_t)(m0 + half * 128 + row) * EMB + kt + gq * 8,
              &lsA[t & 1][half * 8192 + s * 8]);
    }
  };
  auto stB = [&](int t, int half) {
    const int kt = t * BK;
    #pragma unroll
    for (int ii = 0; ii < 2; ++ii) {
      int s = ii * 512 + tid;
      int row = s >> 3, gq = (s & 7) ^ (row & 7);
      async16(wt + (size_t)(n0 + half * 128 + row) * EMB + kt + gq * 8,
              &lsB[t & 1][half * 8192 + s * 8]);
    }
  };

  f32x4 acc[8][4];
  #pragma unroll
  for (int i = 0; i < 8; ++i)
    #pragma unroll
    for (int j = 0; j < 4; ++j)
      acc[i][j] = f32x4{0.f, 0.f, 0.f, 0.f};

  // per-lane LDS read offsets (u16 units)
  int rbase[4];
  #pragma unroll
  for (int nf = 0; nf < 4; ++nf)
    rbase[nf] = ((wc >> 1) * 128 + (2 * (wc & 1) + (nf >> 1)) * 16 + (nf & 1) * 64 + lq) * BK;
  const int aRow0 = (wr * 128 + lq) * BK;
  int qsw[2];
  qsw[0] = ((0 + lr) ^ (lq & 7)) * 8;
  qsw[1] = ((4 + lr) ^ (lq & 7)) * 8;

  // prologue: A0(4) B0(4) B1(4) loads; vmcnt(4) -> A0+B0 landed, B1 in flight
  stA(0, 0); stA(0, 1); stB(0, 0); stB(0, 1); stB(1, 0); stB(1, 1);
  asm volatile("s_waitcnt vmcnt(4)" ::: "memory");
  GBAR();

  for (int ti = 0; ti < NT_K / 2; ++ti) {
    const int t0 = 2 * ti, t1 = t0 + 1;
    const bool notlast = (ti < NT_K / 2 - 1);

    #pragma unroll
    for (int hp = 0; hp < 2; ++hp) {      // hp=0: tile t0 (buf0), hp=1: t1 (buf1)
      const u16* Ap = lsA[hp];
      const u16* Bp = lsB[hp];
      bf16x8 bfr[4][2];

      #pragma unroll
      for (int q = 0; q < 4; ++q) {
        // ---- ds_read register subtile ----
        if (q == 0) {
          #pragma unroll
          for (int nf = 0; nf < 4; ++nf)
            #pragma unroll
            for (int kk = 0; kk < 2; ++kk)
              bfr[nf][kk] = *(const bf16x8*)(Bp + rbase[nf] + qsw[kk]);
        }
        bf16x8 af[2][2];
        #pragma unroll
        for (int mfl = 0; mfl < 2; ++mfl)
          #pragma unroll
          for (int kk = 0; kk < 2; ++kk)
            af[mfl][kk] = *(const bf16x8*)(Ap + aRow0 + (q * 32 + mfl * 16) * BK + qsw[kk]);

        // ---- stage one half-tile ----
        if (hp == 0) {
          if      (q == 0) stA(t1, 0);
          else if (q == 1) stA(t1, 1);
          else if (q == 2) { if (notlast) stB(t0 + 2, 0); }
          else {
            if (notlast) {
              stB(t0 + 2, 1);
              asm volatile("s_waitcnt vmcnt(4)" ::: "memory");  // lands A(t1)+B(t1)
            } else {
              asm volatile("s_waitcnt vmcnt(0)" ::: "memory");  // drain for final tile
            }
          }
        } else {
          if      (q == 0) { if (notlast) stA(t0 + 2, 0); }
          else if (q == 1) { if (notlast) stA(t0 + 2, 1); }
          else if (q == 2) { if (notlast) stB(t1 + 2, 0); }
          else {
            if (notlast) {
              stB(t1 + 2, 1);
              asm volatile("s_waitcnt vmcnt(4)" ::: "memory");  // lands tile t0+2
            }
          }
        }
        if (q == 0) asm volatile("s_waitcnt lgkmcnt(8)" ::: "memory");  // partial drain of 12-read phase

        GBAR();
        WLGKM0();
        __builtin_amdgcn_s_setprio(1);
        #pragma unroll
        for (int kk = 0; kk < 2; ++kk)
          #pragma unroll
          for (int mfl = 0; mfl < 2; ++mfl)
            #pragma unroll
            for (int nf = 0; nf < 4; ++nf)
              acc[q * 2 + mfl][nf] = __builtin_amdgcn_mfma_f32_16x16x32_bf16(
                  af[mfl][kk], bfr[nf][kk], acc[q * 2 + mfl][nf], 0, 0, 0);
        __builtin_amdgcn_s_setprio(0);
        GBAR();
      }
    }
  }

  // ---------------- epilogue (fused bias + RoPE / V-transpose) ----------------
  const int w = n0 >> 11;                  // 0=q, 1=k, 2=v (BN=256 divides 2048)
  const int h = ((n0 & 2047) >> 7) + (wc >> 1);
  float bb[4];
  int dloc[4];
  #pragma unroll
  for (int nf = 0; nf < 4; ++nf) {
    dloc[nf] = (2 * (wc & 1) + (nf >> 1)) * 16 + (nf & 1) * 64 + lq;   // d within head
    bb[nf] = bias[n0 + (wc >> 1) * 128 + dloc[nf]];
  }

  if (w == 2) {
    // V: transpose to [B,H,D,SEQP], 4 consecutive s per 8B store
    #pragma unroll
    for (int mf = 0; mf < 8; ++mf) {
      int mg0 = m0 + wr * 128 + mf * 16 + lr * 4;
      int b = mg0 >> 11, s0 = mg0 & 2047;
      #pragma unroll
      for (int nf = 0; nf < 4; ++nf) {
        int d = dloc[nf];
        ushort4 pk;
        pk.x = f2bf(acc[mf][nf][0] + bb[nf]);
        pk.y = f2bf(acc[mf][nf][1] + bb[nf]);
        pk.z = f2bf(acc[mf][nf][2] + bb[nf]);
        pk.w = f2bf(acc[mf][nf][3] + bb[nf]);
        *(ushort4*)(vbt + ((size_t)(b * NH + h) * HD + d) * SEQP + s0) = pk;
      }
    }
  } else {
    u16* basep = (w == 0) ? qb : kb;
    const float qs = (w == 0) ? 0.12751569843736827f : 1.0f;  // log2(e)/sqrt(128) into q
    #pragma unroll
    for (int mf = 0; mf < 8; ++mf)
      #pragma unroll
      for (int r = 0; r < 4; ++r) {
        int mg = m0 + wr * 128 + mf * 16 + lr * 4 + r;
        int b = mg >> 11, s = mg & 2047;
        u16* dst = basep + ((size_t)(b * NH + h) * SEQ + s) * HD;
        #pragma unroll
        for (int pl = 0; pl < 2; ++pl) {
          int d1 = (2 * (wc & 1) + pl) * 16 + lq;      // in [0,64); partner d1+64
          float c1 = acc[mf][2 * pl][r]     + bb[2 * pl];
          float c2 = acc[mf][2 * pl + 1][r] + bb[2 * pl + 1];
          float2 s1 = tab[s * HD + d1];
          float2 s2 = tab[s * HD + d1 + 64];
          dst[d1]      = f2bf((c1 * s1.x - c2 * s1.y) * qs);
          dst[d1 + 64] = f2bf((c2 * s2.x + c1 * s2.y) * qs);
        }
      }
  }
}

// ---------------- flash attention (unchanged; round-4 structure + XCD-aware remap) ----------------
__global__ __launch_bounds__(128, 2) void k_flash(
    const u16* __restrict__ qb, const u16* __restrict__ kb,
    const u16* __restrict__ vbt, float* __restrict__ out)
{
  __shared__ __align__(16) u16 lsK[2][KT * HD];   // [key][d] 16B-grp ^= key&7    (8 KB x2)
  __shared__ __align__(16) u16 lsV[2][HD * KT];   // [d][key] 16B-grp ^= (d>>1)&3 (8 KB x2)
  __shared__ __align__(16) u16 lsP[2][WQ * KT];   // per-wave [qrow][key], 8B-grp ^= row&6

  const int tid = threadIdx.x;            // 0..127
  const int wave = tid >> 6, lane = tid & 63;
  const int lq = lane & 15, lr = lane >> 4;
  const int i = blockIdx.x;               // 0..1023
  const int xcd = i & 7, j = i >> 3;      // j: 0..127
  const int bh = xcd * 4 + (j >> 5);      // 4 heads per XCD
  const int q0 = (j & 31) * QT;
  const u16* Qg = qb + ((size_t)bh * SEQ + q0 + wave * WQ) * HD;
  const u16* Kg = kb + (size_t)bh * SEQ * HD;
  const u16* Vg = vbt + (size_t)bh * HD * SEQP;

  auto stage = [&](int tile, int buf) {
    const int k0 = tile * KT;
    #pragma unroll
    for (int ii = 0; ii < 4; ++ii) {
      int c = tid + ii * 128;
      int key = c >> 4, grp = c & 15;
      async16(Kg + (size_t)(k0 + key) * HD + ((grp ^ (key & 7)) * 8), lsK[buf] + c * 8);
    }
    #pragma unroll
    for (int ii = 0; ii < 4; ++ii) {
      int c = tid + ii * 128;
      int d = c >> 2, g2 = c & 3;
      async16(Vg + (size_t)d * SEQP + k0 + ((g2 ^ ((d >> 1) & 3)) * 8), lsV[buf] + c * 8);
    }
  };

  stage(0, 0);

  bf16x8 qf[2][4];
  #pragma unroll
  for (int qq = 0; qq < 2; ++qq)
    #pragma unroll
    for (int ks = 0; ks < 4; ++ks)
      qf[qq][ks] = *(const bf16x8*)(Qg + (size_t)(qq * 16 + lq) * HD + ks * 32 + lr * 8);

  f32x4 acc_o[2][8];
  float lsum[2] = {0.f, 0.f};
  #pragma unroll
  for (int mb = 0; mb < 2; ++mb)
    #pragma unroll
    for (int nb = 0; nb < 8; ++nb) acc_o[mb][nb] = f32x4{0.f, 0.f, 0.f, 0.f};

  for (int t = 0; t < NTILE; ++t) {
    const int p = t & 1;
    __syncthreads();                 // drains stage(t); all waves done with buf 1-p
    if (t + 1 < NTILE) stage(t + 1, 1 - p);

    // S^T = K Q^T : 32 keys x 32 q-rows per wave
    f32x4 sacc[2][2];
    #pragma unroll
    for (int kbi = 0; kbi < 2; ++kbi)
      #pragma unroll
      for (int qq = 0; qq < 2; ++qq) sacc[kbi][qq] = f32x4{0.f, 0.f, 0.f, 0.f};
    #pragma unroll
    for (int ks = 0; ks < 4; ++ks) {
      bf16x8 kf[2];
      #pragma unroll
      for (int kbi = 0; kbi < 2; ++kbi) {
        int key = kbi * 16 + lq;
        int g = (ks * 4 + lr) ^ (key & 7);
        kf[kbi] = *(const bf16x8*)(lsK[p] + key * HD + g * 8);
      }
      #pragma unroll
      for (int kbi = 0; kbi < 2; ++kbi)
        #pragma unroll
        for (int qq = 0; qq < 2; ++qq)
          sacc[kbi][qq] = __builtin_amdgcn_mfma_f32_16x16x32_bf16(kf[kbi], qf[qq][ks], sacc[kbi][qq], 0, 0, 0);
    }

    // P = exp2(S) (log2e folded into q); packed b64 writes (4 consecutive keys/lane)
    #pragma unroll
    for (int kbi = 0; kbi < 2; ++kbi)
      #pragma unroll
      for (int qq = 0; qq < 2; ++qq) {
        float p0 = __builtin_amdgcn_exp2f(sacc[kbi][qq][0]);
        float p1 = __builtin_amdgcn_exp2f(sacc[kbi][qq][1]);
        float p2 = __builtin_amdgcn_exp2f(sacc[kbi][qq][2]);
        float p3 = __builtin_amdgcn_exp2f(sacc[kbi][qq][3]);
        lsum[qq] += (p0 + p1) + (p2 + p3);
        int row = qq * 16 + lq;
        int g = kbi * 4 + lr;
        int gp = g ^ (row & 6);
        uint2 pk;
        pk.x = (uint32_t)f2bf(p0) | ((uint32_t)f2bf(p1) << 16);
        pk.y = (uint32_t)f2bf(p2) | ((uint32_t)f2bf(p3) << 16);
        *(uint2*)(lsP[wave] + row * KT + gp * 4) = pk;
      }

    // O += P V
    bf16x8 ap[2];
    #pragma unroll
    for (int mb = 0; mb < 2; ++mb) {
      int row = mb * 16 + lq;
      int gp = (2 * lr) ^ (row & 6);
      ap[mb] = *(const bf16x8*)(lsP[wave] + row * KT + gp * 4);
    }
    #pragma unroll
    for (int nb = 0; nb < 8; ++nb) {
      int d = nb * 16 + lq;
      int g2 = lr ^ ((d >> 1) & 3);
      bf16x8 bv = *(const bf16x8*)(lsV[p] + d * KT + g2 * 8);
      #pragma unroll
      for (int mb = 0; mb < 2; ++mb)
        acc_o[mb][nb] = __builtin_amdgcn_mfma_f32_16x16x32_bf16(ap[mb], bv[0] == bv[0] ? bv : bv, acc_o[mb][nb], 0, 0, 0);
    }
  }

  float inv[2];
  #pragma unroll
  for (int qq = 0; qq < 2; ++qq) {
    float s = lsum[qq];
    s += __shfl_xor(s, 16);
    s += __shfl_xor(s, 32);
    inv[qq] = 1.0f / s;
  }
  const int b = bh >> 4, h = bh & 15;
  #pragma unroll
  for (int mb = 0; mb < 2; ++mb)
    #pragma unroll
    for (int r = 0; r < 4; ++r) {
      float iv = __shfl(inv[mb], lr * 4 + r);
      int row = wave * WQ + mb * 16 + lr * 4 + r;
      int sq = q0 + row;
      float* op = out + (((size_t)b * SEQ + sq) * NH + h) * HD;
      #pragma unroll
      for (int nb = 0; nb < 8; ++nb)
        op[nb * 16 + lq] = acc_o[mb][nb][r] * iv;
    }
}

// ---------------- launch ----------------

extern "C" void kernel_launch(void* const* d_in, const int* in_sizes, int n_in,
                              void* d_out, int out_size, void* d_ws, size_t ws_size,
                              hipStream_t stream) {
  (void)in_sizes; (void)n_in; (void)out_size; (void)ws_size;
  const float* x    = (const float*)d_in[0];
  const float* W    = (const float*)d_in[1];
  const float* bias = (const float*)d_in[2];
  float* out = (float*)d_out;

  char* p = (char*)d_ws;
  u16* xb  = (u16*)p;  p += (size_t)MM * EMB * 2;                     // 16.8 MB
  u16* wt  = (u16*)p;  p += (size_t)N3 * EMB * 2;                     // 25.2 MB
  u16* qb  = (u16*)p;  p += (size_t)NUM_B * NH * SEQ * HD * 2;        // 16.8 MB
  u16* kb  = (u16*)p;  p += (size_t)NUM_B * NH * SEQ * HD * 2;        // 16.8 MB
  u16* vbt = (u16*)p;  p += (size_t)NUM_B * NH * HD * SEQP * 2;       // 17.0 MB
  float2* tab = (float2*)p;                                           // 2.1 MB

  k_cvt_bf16<<<(MM * EMB / 4 + 255) / 256, 256, 0, stream>>>(x, xb, MM * EMB / 4);
  k_transpose_w<<<dim3(N3 / 32, EMB / 32), dim3(32, 8), 0, stream>>>(W, wt);
  k_sincos<<<(SEQ * HD) / 256, 256, 0, stream>>>(tab);
  k_gemm_qkv<<<dim3(N3 / BN, MM / BM), 512, 0, stream>>>(xb, wt, bias, tab, qb, kb, vbt);
  k_flash<<<SEQ / QT * NUM_B * NH, 128, 0, stream>>>(qb, kb, vbt, out);
}